// Round 1
// baseline (3076.900 us; speedup 1.0000x reference)
//
#include <hip/hip_runtime.h>
#include <hip/hip_bf16.h>

// Bidirectional GRU encoder, MI355X gfx950.
// Phase 1: prep (transpose+cast weights, gather embeddings) + one big MFMA GEMM xW = A @ Wcat.
// Phase 2: 256 per-step launches, each doing fwd+bwd GRU step with 16x16x32 bf16 MFMA.

typedef __attribute__((ext_vector_type(8))) short bf16x8;   // 8 x bf16 (4 VGPRs)
typedef __attribute__((ext_vector_type(4))) float f32x4;    // MFMA accumulator

__device__ __forceinline__ f32x4 mfma_bf16(bf16x8 a, bf16x8 b, f32x4 c) {
  return __builtin_amdgcn_mfma_f32_16x16x32_bf16(a, b, c, 0, 0, 0);
}

// ---------------- prep kernels ----------------

// dst[c][r] = (bf16)src[r][c];  src: [R][C] f32 row-major, dst: [C][R] bf16 row-major
__global__ __launch_bounds__(256) void transpose_cast(const float* __restrict__ src,
                                                      __hip_bfloat16* __restrict__ dst,
                                                      int R, int C) {
  __shared__ float tile[32][33];
  const int tid = threadIdx.x;
  const int bc = blockIdx.x * 32;   // col block of src
  const int br = blockIdx.y * 32;   // row block of src
#pragma unroll
  for (int i = 0; i < 4; ++i) {
    int idx = tid + i * 256;
    int r = idx >> 5, c = idx & 31;
    tile[r][c] = src[(size_t)(br + r) * C + bc + c];
  }
  __syncthreads();
#pragma unroll
  for (int i = 0; i < 4; ++i) {
    int idx = tid + i * 256;
    int r = idx >> 5, c = idx & 31;  // r: local out-row (orig col), c: local out-col (orig row)
    dst[(size_t)(bc + r) * R + br + c] = __float2bfloat16(tile[c][r]);
  }
}

// A[t*32+b][e] = (bf16) emb[x[b][t]][e];  A: [8192][512] bf16
__global__ __launch_bounds__(256) void gather_embed(const int* __restrict__ x,
                                                    const float* __restrict__ emb,
                                                    __hip_bfloat16* __restrict__ A) {
  int ch = blockIdx.x * 256 + threadIdx.x;      // [0, 8192*64)
  int row = ch >> 6, seg = ch & 63;             // 64 chunks of 8 elems per row
  int b = row & 31, t = row >> 5;
  int idx = x[b * 256 + t];
  const float* s = emb + (size_t)idx * 512 + seg * 8;
  float4 f0 = *(const float4*)(s);
  float4 f1 = *(const float4*)(s + 4);
  __hip_bfloat16 h[8];
  h[0] = __float2bfloat16(f0.x); h[1] = __float2bfloat16(f0.y);
  h[2] = __float2bfloat16(f0.z); h[3] = __float2bfloat16(f0.w);
  h[4] = __float2bfloat16(f1.x); h[5] = __float2bfloat16(f1.y);
  h[6] = __float2bfloat16(f1.z); h[7] = __float2bfloat16(f1.w);
  *(uint4*)(A + (size_t)row * 512 + seg * 8) = *(const uint4*)h;
}

// h32[pp=0][d][j] = h0_d[j]; h16 likewise
__global__ __launch_bounds__(256) void init_h(const float* __restrict__ h0f,
                                              const float* __restrict__ h0b,
                                              float* __restrict__ h32,
                                              __hip_bfloat16* __restrict__ h16) {
  int i = blockIdx.x * 256 + threadIdx.x;   // [0, 65536)
  int d = i >> 15, j = i & 32767;
  float v = d ? h0b[j] : h0f[j];
  h32[d * 32768 + j] = v;
  h16[d * 32768 + j] = __float2bfloat16(v);
}

// ---------------- big GEMM: xW[8192][6144] = A[8192][512] @ WT[6144][512]^T ----------------
// 128x128 tile, BK=32, 4 waves each 64x64 (4x4 tiles of 16x16x32).
__global__ __launch_bounds__(256) void gemm_xw(const __hip_bfloat16* __restrict__ A,
                                               const __hip_bfloat16* __restrict__ B,
                                               __hip_bfloat16* __restrict__ C) {
  __shared__ char sm[2 * 128 * 80];   // A tile [128][32+8pad] bf16, B tile same
  const int tid = threadIdx.x;
  const int bn = blockIdx.x, bm = blockIdx.y;
  const int l = tid & 63, w = tid >> 6;
  const int wm = w & 1, wn = w >> 1;
  const int lr = l & 15, lk = l >> 4;
  f32x4 acc[4][4] = {};
  for (int k0 = 0; k0 < 512; k0 += 32) {
    __syncthreads();
#pragma unroll
    for (int i = 0; i < 2; ++i) {
      int ch = tid + i * 256;              // [0,512): 128 rows x 4 chunks
      int row = ch >> 2, kq = ch & 3;
      uint4 va = *(const uint4*)(A + (size_t)(bm * 128 + row) * 512 + k0 + kq * 8);
      *(uint4*)(sm + row * 80 + kq * 16) = va;
      uint4 vb = *(const uint4*)(B + (size_t)(bn * 128 + row) * 512 + k0 + kq * 8);
      *(uint4*)(sm + 10240 + row * 80 + kq * 16) = vb;
    }
    __syncthreads();
    bf16x8 af[4], bfr[4];
#pragma unroll
    for (int m = 0; m < 4; ++m)
      af[m] = *(const bf16x8*)(sm + (wm * 64 + m * 16 + lr) * 80 + lk * 16);
#pragma unroll
    for (int n = 0; n < 4; ++n)
      bfr[n] = *(const bf16x8*)(sm + 10240 + (wn * 64 + n * 16 + lr) * 80 + lk * 16);
#pragma unroll
    for (int m = 0; m < 4; ++m)
#pragma unroll
      for (int n = 0; n < 4; ++n)
        acc[m][n] = mfma_bf16(af[m], bfr[n], acc[m][n]);
  }
#pragma unroll
  for (int m = 0; m < 4; ++m)
#pragma unroll
    for (int n = 0; n < 4; ++n)
#pragma unroll
      for (int v = 0; v < 4; ++v) {
        int row = bm * 128 + wm * 64 + m * 16 + lk * 4 + v;
        int col = bn * 128 + wn * 64 + n * 16 + lr;
        C[(size_t)row * 6144 + col] = __float2bfloat16(acc[m][n][v]);
      }
}

// ---------------- GRU step kernel (one launch per time step, both directions) ----------------
// grid (64, 2): blockIdx.x -> 16 h-columns, blockIdx.y -> direction. 128 threads = 2 waves.
// Wave w handles batch rows [16w,16w+16); computes hU for its 16 cols x 3 gates via MFMA,
// operands read straight from global (L2-resident).
__global__ __launch_bounds__(128) void gru_step(const __hip_bfloat16* __restrict__ xW,
                                                const __hip_bfloat16* __restrict__ UT,
                                                const float* __restrict__ bias_f,
                                                const float* __restrict__ bias_b,
                                                const float* __restrict__ h32in,
                                                float* __restrict__ h32out,
                                                const __hip_bfloat16* __restrict__ h16in,
                                                __hip_bfloat16* __restrict__ h16out,
                                                float* __restrict__ out, int s) {
  const int tid = threadIdx.x;
  const int dir = blockIdx.y;
  const int c0 = blockIdx.x * 16;
  const int l = tid & 63, w = tid >> 6;
  const int lr = l & 15, lk = l >> 4;

  const __hip_bfloat16* hin = h16in + dir * 32768;
  // B operand rows of UT: row = dir*3072 + g*1024 + (c0+lr)
  const __hip_bfloat16* Ubase = UT + (size_t)(dir * 3072 + c0 + lr) * 1024;

  f32x4 acc[3] = {};
  for (int k0 = 0; k0 < 1024; k0 += 32) {
    bf16x8 a = *(const bf16x8*)(hin + (size_t)(w * 16 + lr) * 1024 + k0 + lk * 8);
#pragma unroll
    for (int g = 0; g < 3; ++g) {
      bf16x8 b = *(const bf16x8*)(Ubase + (size_t)g * 1024 * 1024 + k0 + lk * 8);
      acc[g] = mfma_bf16(a, b, acc[g]);
    }
  }

  const int t = dir ? (255 - s) : s;
  const float* bias = dir ? bias_b : bias_f;
  const int col = c0 + lr;                 // h-column in [0,1024)
  const float b0z = bias[col],        b0r = bias[1024 + col], b0n = bias[2048 + col];
  const float b1z = bias[3072 + col], b1r = bias[4096 + col], b1n = bias[5120 + col];

#pragma unroll
  for (int v = 0; v < 4; ++v) {
    int b = w * 16 + lk * 4 + v;           // batch row (C layout: row = 4*(l>>4)+reg)
    size_t xb = (size_t)(t * 32 + b) * 6144 + dir * 3072 + col;
    float xz = __bfloat162float(xW[xb]);
    float xr = __bfloat162float(xW[xb + 1024]);
    float xn = __bfloat162float(xW[xb + 2048]);
    float z = 1.f / (1.f + expf(-(xz + b0z + acc[0][v] + b1z)));
    float r = 1.f / (1.f + expf(-(xr + b0r + acc[1][v] + b1r)));
    float n = tanhf(xn + b0n + r * (acc[2][v] + b1n));
    float hp = h32in[dir * 32768 + b * 1024 + col];
    float hn = z * hp + (1.f - z) * n;
    out[((size_t)b * 256 + t) * 2048 + dir * 1024 + col] = hn;
    h32out[dir * 32768 + b * 1024 + col] = hn;
    h16out[dir * 32768 + b * 1024 + col] = __float2bfloat16(hn);
    if (s == 255) out[16777216 + dir * 32768 + b * 1024 + col] = hn;  // h_f / h_b outputs
  }
}

// ---------------- host ----------------

extern "C" void kernel_launch(void* const* d_in, const int* in_sizes, int n_in,
                              void* d_out, int out_size, void* d_ws, size_t ws_size,
                              hipStream_t stream) {
  const int*   x    = (const int*)d_in[0];
  const float* emb  = (const float*)d_in[1];
  const float* W_f  = (const float*)d_in[2];
  const float* U_f  = (const float*)d_in[3];
  const float* b_f  = (const float*)d_in[4];
  const float* W_b  = (const float*)d_in[5];
  const float* U_b  = (const float*)d_in[6];
  const float* b_b  = (const float*)d_in[7];
  const float* h0_f = (const float*)d_in[8];
  const float* h0_b = (const float*)d_in[9];
  float* out = (float*)d_out;
  char* ws = (char*)d_ws;

  const size_t SZ_A  = (size_t)8192 * 512 * 2;     //   8,388,608
  const size_t SZ_WT = (size_t)6144 * 512 * 2;     //   6,291,456
  const size_t SZ_UT = (size_t)6144 * 1024 * 2;    //  12,582,912
  const size_t SZ_XW = (size_t)8192 * 6144 * 2;    // 100,663,296
  const size_t SZ_H32 = (size_t)2 * 2 * 32 * 1024 * 4;

  __hip_bfloat16* A   = (__hip_bfloat16*)(ws);
  __hip_bfloat16* WT  = (__hip_bfloat16*)(ws + SZ_A);
  __hip_bfloat16* UT  = (__hip_bfloat16*)(ws + SZ_A + SZ_WT);
  __hip_bfloat16* XW  = (__hip_bfloat16*)(ws + SZ_A + SZ_WT + SZ_UT);
  float*          H32 = (float*)(ws + SZ_A + SZ_WT + SZ_UT + SZ_XW);
  __hip_bfloat16* H16 = (__hip_bfloat16*)(ws + SZ_A + SZ_WT + SZ_UT + SZ_XW + SZ_H32);

  // prep
  transpose_cast<<<dim3(96, 16), 256, 0, stream>>>(W_f, WT, 512, 3072);
  transpose_cast<<<dim3(96, 16), 256, 0, stream>>>(W_b, WT + (size_t)3072 * 512, 512, 3072);
  transpose_cast<<<dim3(96, 32), 256, 0, stream>>>(U_f, UT, 1024, 3072);
  transpose_cast<<<dim3(96, 32), 256, 0, stream>>>(U_b, UT + (size_t)3072 * 1024, 1024, 3072);
  gather_embed<<<2048, 256, 0, stream>>>(x, emb, A);
  init_h<<<256, 256, 0, stream>>>(h0_f, h0_b, H32, H16);

  // xW = A @ WT^T
  gemm_xw<<<dim3(48, 64), 256, 0, stream>>>(A, WT, XW);

  // recurrence: 256 steps, both directions per launch
  for (int s = 0; s < 256; ++s) {
    const float* hin32 = H32 + (size_t)(s & 1) * 65536;
    float* hout32      = H32 + (size_t)((s & 1) ^ 1) * 65536;
    const __hip_bfloat16* hin16 = H16 + (size_t)(s & 1) * 65536;
    __hip_bfloat16* hout16      = H16 + (size_t)((s & 1) ^ 1) * 65536;
    gru_step<<<dim3(64, 2), 128, 0, stream>>>(XW, UT, b_f, b_b,
                                              hin32, hout32, hin16, hout16, out, s);
  }
}